// Round 2
// baseline (728.235 us; speedup 1.0000x reference)
//
#include <hip/hip_runtime.h>

#define N_NODES 100000
#define N_FEATS 256
#define OUT_DIM 64
#define NNZ_X   1280000
#define N_EDGES 1600000

// ---------------- JAX threefry2x32 replication (PARTITIONABLE mode) ----------------
// jax.random.uniform(jax.random.key(42), (NNZ_X,)) with jax_threefry_partitionable=True
// (default since JAX 0.5):
//   key = (0, 42)
//   per element i: counter = 64-bit flat index -> (hi, lo) = (0, i)
//   (o0, o1) = threefry2x32(key, (hi, lo))
//   bits = o0 ^ o1                      // 32-bit output path
//   u = bitcast_f32((bits >> 9) | 0x3f800000) - 1.0
__device__ __forceinline__ unsigned rotl32(unsigned x, unsigned d) {
    return (x << d) | (x >> (32u - d));
}

__device__ __forceinline__ float jax_uniform_42(unsigned e) {
    unsigned x0 = 0u, x1 = e;
    const unsigned ks0 = 0u, ks1 = 42u, ks2 = 0u ^ 42u ^ 0x1BD11BDAu;
    x0 += ks0; x1 += ks1;
#define TF_R(r) { x0 += x1; x1 = rotl32(x1, r); x1 ^= x0; }
    TF_R(13) TF_R(15) TF_R(26) TF_R(6)
    x0 += ks1; x1 += ks2 + 1u;
    TF_R(17) TF_R(29) TF_R(16) TF_R(24)
    x0 += ks2; x1 += ks0 + 2u;
    TF_R(13) TF_R(15) TF_R(26) TF_R(6)
    x0 += ks0; x1 += ks1 + 3u;
    TF_R(17) TF_R(29) TF_R(16) TF_R(24)
    x0 += ks1; x1 += ks2 + 4u;
    TF_R(13) TF_R(15) TF_R(26) TF_R(6)
    x0 += ks2; x1 += ks0 + 5u;
#undef TF_R
    unsigned bits = x0 ^ x1;
    return __uint_as_float((bits >> 9) | 0x3f800000u) - 1.0f;
}

// dropout: v[e] = keep ? feat_values[e] * (1/0.9) : 0
__global__ void dropout_kernel(const float* __restrict__ feat_values,
                               float* __restrict__ v) {
    unsigned e = blockIdx.x * blockDim.x + threadIdx.x;
    if (e >= NNZ_X) return;
    float u = jax_uniform_42(e);
    // replicate reference exactly: keep = floor(0.9f + u) != 0
    float keep = floorf(0.9f + u);
    v[e] = (keep != 0.0f) ? feat_values[e] * (float)(1.0 / 0.9) : 0.0f;
}

// SpMM1: one wave per nonzero, lane = output dim.
// xw[row, lane] += v[e] * W[col, lane]
__global__ void spmm1_kernel(const float* __restrict__ v,
                             const int* __restrict__ rows,
                             const int* __restrict__ cols,
                             const float* __restrict__ W,
                             float* __restrict__ xw) {
    unsigned wave = blockIdx.x * 4u + (threadIdx.x >> 6);
    unsigned lane = threadIdx.x & 63u;
    if (wave >= NNZ_X) return;
    float val = v[wave];
    if (val == 0.0f) return;            // dropped entries contribute nothing
    unsigned row = (unsigned)rows[wave];
    unsigned col = (unsigned)cols[wave];
    float w = W[col * OUT_DIM + lane];
    atomicAdd(&xw[row * OUT_DIM + lane], val * w);
}

// SpMM2: one wave per edge, lane = output dim.
// out[row, lane] += a[e] * xw[col, lane]
__global__ void spmm2_kernel(const float* __restrict__ a,
                             const int* __restrict__ rows,
                             const int* __restrict__ cols,
                             const float* __restrict__ xw,
                             float* __restrict__ out) {
    unsigned wave = blockIdx.x * 4u + (threadIdx.x >> 6);
    unsigned lane = threadIdx.x & 63u;
    if (wave >= N_EDGES) return;
    float av = a[wave];
    unsigned row = (unsigned)rows[wave];
    unsigned col = (unsigned)cols[wave];
    float x = xw[col * OUT_DIM + lane];
    atomicAdd(&out[row * OUT_DIM + lane], av * x);
}

__global__ void relu_kernel(float* __restrict__ out) {
    unsigned i = blockIdx.x * blockDim.x + threadIdx.x;
    if (i >= (N_NODES * OUT_DIM) / 4) return;
    float4* o4 = (float4*)out;
    float4 t = o4[i];
    t.x = fmaxf(t.x, 0.0f);
    t.y = fmaxf(t.y, 0.0f);
    t.z = fmaxf(t.z, 0.0f);
    t.w = fmaxf(t.w, 0.0f);
    o4[i] = t;
}

extern "C" void kernel_launch(void* const* d_in, const int* in_sizes, int n_in,
                              void* d_out, int out_size, void* d_ws, size_t ws_size,
                              hipStream_t stream) {
    const float* feat_values = (const float*)d_in[0];
    const float* W           = (const float*)d_in[1];
    const float* adj_values  = (const float*)d_in[2];
    const int*   feat_rows   = (const int*)d_in[3];
    const int*   feat_cols   = (const int*)d_in[4];
    const int*   adj_rows    = (const int*)d_in[5];
    const int*   adj_cols    = (const int*)d_in[6];
    float* out = (float*)d_out;

    // workspace layout: v[NNZ_X] | xw[N_NODES * OUT_DIM]
    float* v  = (float*)d_ws;
    float* xw = (float*)((char*)d_ws + (size_t)NNZ_X * sizeof(float));

    // zero the accumulators (ws/out are poisoned 0xAA before every launch)
    hipMemsetAsync(xw, 0, (size_t)N_NODES * OUT_DIM * sizeof(float), stream);
    hipMemsetAsync(out, 0, (size_t)N_NODES * OUT_DIM * sizeof(float), stream);

    dropout_kernel<<<(NNZ_X + 255) / 256, 256, 0, stream>>>(feat_values, v);

    // one wave (64 lanes) per nonzero: 4 waves per 256-thread block
    spmm1_kernel<<<(NNZ_X + 3) / 4, 256, 0, stream>>>(v, feat_rows, feat_cols, W, xw);

    spmm2_kernel<<<(N_EDGES + 3) / 4, 256, 0, stream>>>(adj_values, adj_rows, adj_cols, xw, out);

    relu_kernel<<<((N_NODES * OUT_DIM / 4) + 255) / 256, 256, 0, stream>>>(out);
}

// Round 3
// 592.752 us; speedup vs baseline: 1.2286x; 1.2286x over previous
//
#include <hip/hip_runtime.h>

#define N_NODES 100000
#define N_FEATS 256
#define OUT_DIM 64
#define NNZ_X   1280000
#define N_EDGES 1600000

// ---------------- JAX threefry2x32 (partitionable mode, verified R2) ----------------
__device__ __forceinline__ unsigned rotl32(unsigned x, unsigned d) {
    return (x << d) | (x >> (32u - d));
}

__device__ __forceinline__ float jax_uniform_42(unsigned e) {
    unsigned x0 = 0u, x1 = e;
    const unsigned ks0 = 0u, ks1 = 42u, ks2 = 0u ^ 42u ^ 0x1BD11BDAu;
    x0 += ks0; x1 += ks1;
#define TF_R(r) { x0 += x1; x1 = rotl32(x1, r); x1 ^= x0; }
    TF_R(13) TF_R(15) TF_R(26) TF_R(6)
    x0 += ks1; x1 += ks2 + 1u;
    TF_R(17) TF_R(29) TF_R(16) TF_R(24)
    x0 += ks2; x1 += ks0 + 2u;
    TF_R(13) TF_R(15) TF_R(26) TF_R(6)
    x0 += ks0; x1 += ks1 + 3u;
    TF_R(17) TF_R(29) TF_R(16) TF_R(24)
    x0 += ks1; x1 += ks2 + 4u;
    TF_R(13) TF_R(15) TF_R(26) TF_R(6)
    x0 += ks2; x1 += ks0 + 5u;
#undef TF_R
    unsigned bits = x0 ^ x1;
    return __uint_as_float((bits >> 9) | 0x3f800000u) - 1.0f;
}

// ---------------- binning: histogram ----------------
// one thread covers one feat nnz (i < NNZ_X) and one edge (i < N_EDGES)
__global__ void hist_kernel(const int* __restrict__ frows,
                            const int* __restrict__ arows,
                            int* __restrict__ cnt_x,
                            int* __restrict__ cnt_a) {
    unsigned i = blockIdx.x * 256u + threadIdx.x;
    if (i < NNZ_X)   atomicAdd(&cnt_x[frows[i]], 1);
    if (i < N_EDGES) atomicAdd(&cnt_a[arows[i]], 1);
}

// ---------------- 3-phase exclusive scan over N_NODES ints (in place) ----------
// grid.y selects which array (0 = x, 1 = a). 1024 elements / block.
__global__ void scan1_kernel(int* __restrict__ cnt_x, int* __restrict__ cnt_a,
                             int* __restrict__ bsum_x, int* __restrict__ bsum_a) {
    int* cnt  = blockIdx.y ? cnt_a  : cnt_x;
    int* bsum = blockIdx.y ? bsum_a : bsum_x;
    __shared__ int lds[256];
    unsigned base = blockIdx.x * 1024u;
    unsigned t = threadIdx.x;
    int vals[4];
    int sum = 0;
    for (int k = 0; k < 4; k++) {
        unsigned idx = base + t * 4u + k;
        int v = (idx < N_NODES) ? cnt[idx] : 0;
        vals[k] = sum;           // exclusive within thread
        sum += v;
    }
    lds[t] = sum;
    __syncthreads();
    for (int off = 1; off < 256; off <<= 1) {
        int x = (t >= (unsigned)off) ? lds[t - off] : 0;
        __syncthreads();
        lds[t] += x;
        __syncthreads();
    }
    int thread_excl = (t > 0) ? lds[t - 1] : 0;
    if (t == 255) bsum[blockIdx.x] = lds[255];
    for (int k = 0; k < 4; k++) {
        unsigned idx = base + t * 4u + k;
        if (idx < N_NODES) cnt[idx] = thread_excl + vals[k];
    }
}

__global__ void scan2_kernel(int* __restrict__ bsum_x, int* __restrict__ bsum_a, int nb) {
    int* bsum = blockIdx.y ? bsum_a : bsum_x;
    __shared__ int lds[256];
    unsigned t = threadIdx.x;
    int v = (t < (unsigned)nb) ? bsum[t] : 0;
    lds[t] = v;
    __syncthreads();
    for (int off = 1; off < 256; off <<= 1) {
        int x = (t >= (unsigned)off) ? lds[t - off] : 0;
        __syncthreads();
        lds[t] += x;
        __syncthreads();
    }
    if (t < (unsigned)nb) bsum[t] = (t > 0) ? lds[t - 1] : 0;  // exclusive
}

__global__ void scan3_kernel(int* __restrict__ cnt_x, int* __restrict__ cnt_a,
                             const int* __restrict__ bsum_x, const int* __restrict__ bsum_a) {
    int* cnt = blockIdx.y ? cnt_a : cnt_x;
    const int* bsum = blockIdx.y ? bsum_a : bsum_x;
    unsigned i = blockIdx.x * 256u + threadIdx.x;
    if (i < N_NODES) cnt[i] += bsum[i >> 10];
}

// ---------------- scatter into row-sorted order (dropout fused for feats) -------
// After this kernel cursor[r] == row_start[r+1]; start of row r is cursor[r-1] (0 for r=0).
__global__ void scatter_kernel(const float* __restrict__ feat_values,
                               const int* __restrict__ frows, const int* __restrict__ fcols,
                               const float* __restrict__ adj_values,
                               const int* __restrict__ arows, const int* __restrict__ acols,
                               int* __restrict__ cursor_x, int* __restrict__ cursor_a,
                               float2* __restrict__ sorted_x, float2* __restrict__ sorted_a) {
    unsigned i = blockIdx.x * 256u + threadIdx.x;
    if (i < NNZ_X) {
        float u = jax_uniform_42(i);
        float keep = floorf(0.9f + u);
        float v = (keep != 0.0f) ? feat_values[i] * (float)(1.0 / 0.9) : 0.0f;
        int row = frows[i];
        int pos = atomicAdd(&cursor_x[row], 1);
        float2 p; p.x = v; p.y = __int_as_float(fcols[i]);
        sorted_x[pos] = p;
    }
    if (i < N_EDGES) {
        int row = arows[i];
        int pos = atomicAdd(&cursor_a[row], 1);
        float2 p; p.x = adj_values[i]; p.y = __int_as_float(acols[i]);
        sorted_a[pos] = p;
    }
}

// ---------------- SpMM1 (CSR): wave per row, lane = out dim --------------------
__global__ void spmm1_csr(const int* __restrict__ cursor,
                          const float2* __restrict__ sorted,
                          const float* __restrict__ W,
                          float* __restrict__ xw) {
    unsigned row  = blockIdx.x * 4u + (threadIdx.x >> 6);
    unsigned lane = threadIdx.x & 63u;
    if (row >= N_NODES) return;
    int start = (row == 0) ? 0 : cursor[row - 1];
    int end   = cursor[row];
    float acc = 0.0f;
    for (int p = start; p < end; p++) {
        float2 e = sorted[p];
        int col = __float_as_int(e.y);
        acc = fmaf(e.x, W[col * OUT_DIM + lane], acc);
    }
    xw[row * OUT_DIM + lane] = acc;
}

// ---------------- SpMM2 (CSR) + ReLU: wave per row ----------------------------
__global__ void spmm2_csr(const int* __restrict__ cursor,
                          const float2* __restrict__ sorted,
                          const float* __restrict__ xw,
                          float* __restrict__ out) {
    unsigned row  = blockIdx.x * 4u + (threadIdx.x >> 6);
    unsigned lane = threadIdx.x & 63u;
    if (row >= N_NODES) return;
    int start = (row == 0) ? 0 : cursor[row - 1];
    int end   = cursor[row];
    float acc = 0.0f;
    for (int p = start; p < end; p++) {
        float2 e = sorted[p];
        int col = __float_as_int(e.y);
        acc = fmaf(e.x, xw[col * OUT_DIM + lane], acc);
    }
    out[row * OUT_DIM + lane] = fmaxf(acc, 0.0f);
}

extern "C" void kernel_launch(void* const* d_in, const int* in_sizes, int n_in,
                              void* d_out, int out_size, void* d_ws, size_t ws_size,
                              hipStream_t stream) {
    const float* feat_values = (const float*)d_in[0];
    const float* W           = (const float*)d_in[1];
    const float* adj_values  = (const float*)d_in[2];
    const int*   feat_rows   = (const int*)d_in[3];
    const int*   feat_cols   = (const int*)d_in[4];
    const int*   adj_rows    = (const int*)d_in[5];
    const int*   adj_cols    = (const int*)d_in[6];
    float* out = (float*)d_out;

    // ---- workspace layout (bytes) ----
    // cursor_x : 100000 int   @ 0          (400000 B)
    // cursor_a : 100000 int   @ 400000     (400000 B)
    // bsum_x   : 128 int      @ 800000
    // bsum_a   : 128 int      @ 800512
    // sorted_x : NNZ_X float2 @ 801024     (10,240,000 B)
    // sorted_a : N_EDGES f2   @ 11041024   (12,800,000 B)
    // xw       : N*64 float   @ 23841024   (25,600,000 B)  -> total 49,441,024 B
    char* ws = (char*)d_ws;
    int*    cursor_x = (int*)(ws + 0);
    int*    cursor_a = (int*)(ws + 400000);
    int*    bsum_x   = (int*)(ws + 800000);
    int*    bsum_a   = (int*)(ws + 800512);
    float2* sorted_x = (float2*)(ws + 801024);
    float2* sorted_a = (float2*)(ws + 11041024);
    float*  xw       = (float*)(ws + 23841024);

    // zero the counter region (cursors + block sums) in one memset
    hipMemsetAsync(ws, 0, 801024, stream);

    hist_kernel<<<(N_EDGES + 255) / 256, 256, 0, stream>>>(feat_rows, adj_rows, cursor_x, cursor_a);

    dim3 g1((N_NODES + 1023) / 1024, 2);
    scan1_kernel<<<g1, 256, 0, stream>>>(cursor_x, cursor_a, bsum_x, bsum_a);
    dim3 g2(1, 2);
    scan2_kernel<<<g2, 256, 0, stream>>>(bsum_x, bsum_a, (N_NODES + 1023) / 1024);
    dim3 g3((N_NODES + 255) / 256, 2);
    scan3_kernel<<<g3, 256, 0, stream>>>(cursor_x, cursor_a, bsum_x, bsum_a);

    scatter_kernel<<<(N_EDGES + 255) / 256, 256, 0, stream>>>(
        feat_values, feat_rows, feat_cols, adj_values, adj_rows, adj_cols,
        cursor_x, cursor_a, sorted_x, sorted_a);

    spmm1_csr<<<(N_NODES + 3) / 4, 256, 0, stream>>>(cursor_x, sorted_x, W, xw);
    spmm2_csr<<<(N_NODES + 3) / 4, 256, 0, stream>>>(cursor_a, sorted_a, xw, out);
}

// Round 4
// 391.312 us; speedup vs baseline: 1.8610x; 1.5148x over previous
//
#include <hip/hip_runtime.h>

#define N_NODES 100000
#define N_FEATS 256
#define OUT_DIM 64
#define NNZ_X   1280000
#define N_EDGES 1600000
#define NB      391     // ceil(N_NODES/256); bucket = row >> 8
#define CHUNK   4096    // entries per phase-1 block
#define P2CAP   6144    // phase-2 LDS capacity (avg bucket ~4092, +32 sigma margin)

// ---------------- JAX threefry2x32 (partitionable mode, verified R2) ----------------
__device__ __forceinline__ unsigned rotl32(unsigned x, unsigned d) {
    return (x << d) | (x >> (32u - d));
}

__device__ __forceinline__ float jax_uniform_42(unsigned e) {
    unsigned x0 = 0u, x1 = e;
    const unsigned ks0 = 0u, ks1 = 42u, ks2 = 0u ^ 42u ^ 0x1BD11BDAu;
    x0 += ks0; x1 += ks1;
#define TF_R(r) { x0 += x1; x1 = rotl32(x1, r); x1 ^= x0; }
    TF_R(13) TF_R(15) TF_R(26) TF_R(6)
    x0 += ks1; x1 += ks2 + 1u;
    TF_R(17) TF_R(29) TF_R(16) TF_R(24)
    x0 += ks2; x1 += ks0 + 2u;
    TF_R(13) TF_R(15) TF_R(26) TF_R(6)
    x0 += ks0; x1 += ks1 + 3u;
    TF_R(17) TF_R(29) TF_R(16) TF_R(24)
    x0 += ks1; x1 += ks2 + 4u;
    TF_R(13) TF_R(15) TF_R(26) TF_R(6)
    x0 += ks2; x1 += ks0 + 5u;
#undef TF_R
    unsigned bits = x0 ^ x1;
    return __uint_as_float((bits >> 9) | 0x3f800000u) - 1.0f;
}

// ---------------- bucket histogram: LDS-aggregated, ~1.6K global atomics -------
__global__ void bucket_hist(const int* __restrict__ frows,
                            const int* __restrict__ arows,
                            int* __restrict__ bc_x, int* __restrict__ bc_a) {
    const int* rows = blockIdx.y ? arows : frows;
    int* bc         = blockIdx.y ? bc_a  : bc_x;
    const unsigned n = blockIdx.y ? N_EDGES : NNZ_X;
    __shared__ int h[NB];
    for (unsigned b = threadIdx.x; b < NB; b += 256u) h[b] = 0;
    __syncthreads();
    unsigned base = blockIdx.x * CHUNK;
    for (int k = 0; k < CHUNK / 256; k++) {
        unsigned i = base + k * 256u + threadIdx.x;
        if (i < n) atomicAdd(&h[(unsigned)rows[i] >> 8], 1);
    }
    __syncthreads();
    for (unsigned b = threadIdx.x; b < NB; b += 256u)
        if (h[b]) atomicAdd(&bc[b], h[b]);
}

// ---------------- scan 391 bucket totals -> starts + cursors ------------------
__global__ void bucket_scan(const int* __restrict__ bc_x, const int* __restrict__ bc_a,
                            int* __restrict__ bstart_x, int* __restrict__ bstart_a,
                            int* __restrict__ bcur_x, int* __restrict__ bcur_a) {
    const int* bc = blockIdx.y ? bc_a : bc_x;
    int* bst = blockIdx.y ? bstart_a : bstart_x;
    int* bcu = blockIdx.y ? bcur_a : bcur_x;
    __shared__ int c[512];
    __shared__ int s[256];
    unsigned t = threadIdx.x;
    c[2*t]   = (2*t   < NB) ? bc[2*t]   : 0;
    c[2*t+1] = (2*t+1 < NB) ? bc[2*t+1] : 0;
    s[t] = c[2*t] + c[2*t+1];
    __syncthreads();
    for (int off = 1; off < 256; off <<= 1) {
        int v = (t >= (unsigned)off) ? s[t - off] : 0;
        __syncthreads();
        s[t] += v;
        __syncthreads();
    }
    int excl = t ? s[t-1] : 0;
    if (2*t < NB)   { bst[2*t]   = excl;           bcu[2*t]   = excl; }
    if (2*t+1 < NB) { bst[2*t+1] = excl + c[2*t];  bcu[2*t+1] = excl + c[2*t]; }
    if (t == 255) bst[NB] = s[255];
}

// ---------------- phase 1: LDS-binned coarse scatter (coalesced writes) -------
// stages (val, (col<<8)|row_in_bucket) grouped by bucket; dropout fused for X.
__global__ void phase1(const float* __restrict__ fvals, const int* __restrict__ frows,
                       const int* __restrict__ fcols,
                       const float* __restrict__ avals, const int* __restrict__ arows,
                       const int* __restrict__ acols,
                       int* __restrict__ bcur_x, int* __restrict__ bcur_a,
                       float2* __restrict__ gx, float2* __restrict__ ga) {
    const int isA = blockIdx.y;
    const float* vals = isA ? avals : fvals;
    const int* rows   = isA ? arows : frows;
    const int* cols   = isA ? acols : fcols;
    int* bcur         = isA ? bcur_a : bcur_x;
    float2* dst       = isA ? ga : gx;
    const unsigned n  = isA ? N_EDGES : NNZ_X;

    unsigned t = threadIdx.x;
    unsigned base = blockIdx.x * CHUNK;
    if (base >= n) return;   // uniform per block

    __shared__ int cnt[512];
    __shared__ int start[512];
    __shared__ int cur[512];
    __shared__ int gbase[NB];
    __shared__ int s[256];
    __shared__ float2 stage[CHUNK];
    __shared__ unsigned short bArr[CHUNK];

    cnt[2*t] = 0; cnt[2*t+1] = 0;
    __syncthreads();
    // pass 1: count buckets
    for (int k = 0; k < CHUNK / 256; k++) {
        unsigned i = base + k * 256u + t;
        if (i < n) atomicAdd(&cnt[(unsigned)rows[i] >> 8], 1);
    }
    __syncthreads();
    // exclusive scan of cnt (2 elements / thread)
    s[t] = cnt[2*t] + cnt[2*t+1];
    __syncthreads();
    for (int off = 1; off < 256; off <<= 1) {
        int v = (t >= (unsigned)off) ? s[t - off] : 0;
        __syncthreads();
        s[t] += v;
        __syncthreads();
    }
    int excl = t ? s[t-1] : 0;
    int n_valid = s[255];
    start[2*t]   = excl;
    start[2*t+1] = excl + cnt[2*t];
    cur[2*t]     = excl;
    cur[2*t+1]   = excl + cnt[2*t];
    // reserve global space: one atomic per non-empty bucket per block
    for (unsigned b = t; b < NB; b += 256u) {
        int cb = cnt[b];
        if (cb > 0) gbase[b] = atomicAdd(&bcur[b], cb);
    }
    __syncthreads();
    // pass 2: stage into LDS, bucket-grouped
    for (int k = 0; k < CHUNK / 256; k++) {
        unsigned i = base + k * 256u + t;
        if (i < n) {
            unsigned row = (unsigned)rows[i];
            unsigned b = row >> 8;
            float v = vals[i];
            if (!isA) {
                float u = jax_uniform_42(i);
                v = (floorf(0.9f + u) != 0.0f) ? v * (float)(1.0 / 0.9) : 0.0f;
            }
            unsigned packed = ((unsigned)cols[i] << 8) | (row & 255u);
            int p = atomicAdd(&cur[b], 1);
            float2 e; e.x = v; e.y = __int_as_float((int)packed);
            stage[p] = e;
            bArr[p] = (unsigned short)b;
        }
    }
    __syncthreads();
    // write out: consecutive staged slots -> consecutive global (per bucket run)
    for (int k = 0; k < CHUNK / 256; k++) {
        int sidx = k * 256 + (int)t;
        if (sidx < n_valid) {
            unsigned b = bArr[sidx];
            int gpos = gbase[b] + (sidx - start[b]);
            dst[gpos] = stage[sidx];
        }
    }
}

// ---------------- phase 2: per-bucket fine sort (in place) + CSR row starts ---
__global__ void phase2(const int* __restrict__ bstart_x, const int* __restrict__ bstart_a,
                       float2* __restrict__ gx, float2* __restrict__ ga,
                       int* __restrict__ rs_x, int* __restrict__ rs_a) {
    const int isA = blockIdx.y;
    const int* bst = isA ? bstart_a : bstart_x;
    float2* g      = isA ? ga : gx;
    int* rs        = isA ? rs_a : rs_x;
    const int total = isA ? N_EDGES : NNZ_X;

    __shared__ float2 ent[P2CAP];
    __shared__ int hist[256];
    __shared__ int cursor[256];

    unsigned t = threadIdx.x;
    unsigned b = blockIdx.x;
    int s0 = bst[b], s1 = bst[b + 1];
    int n = s1 - s0;
    hist[t] = 0;
    __syncthreads();
    for (int idx = (int)t; idx < n; idx += 256) {
        float2 e = g[s0 + idx];
        ent[idx] = e;
        atomicAdd(&hist[((unsigned)__float_as_int(e.y)) & 255u], 1);
    }
    __syncthreads();
    // inclusive scan of hist (in place)
    for (int off = 1; off < 256; off <<= 1) {
        int v = (t >= (unsigned)off) ? hist[t - off] : 0;
        __syncthreads();
        hist[t] += v;
        __syncthreads();
    }
    int excl = t ? hist[t - 1] : 0;
    cursor[t] = excl;
    unsigned row_global = (b << 8) + t;
    if (row_global < N_NODES) rs[row_global] = s0 + excl;
    if (b == NB - 1 && t == 0) rs[N_NODES] = total;
    __syncthreads();
    // scatter back in place (entries all safely in LDS), store (val, col)
    for (int idx = (int)t; idx < n; idx += 256) {
        float2 e = ent[idx];
        unsigned packed = (unsigned)__float_as_int(e.y);
        int p = atomicAdd(&cursor[packed & 255u], 1);
        float2 o; o.x = e.x; o.y = __int_as_float((int)(packed >> 8));
        g[s0 + p] = o;
    }
}

// ---------------- SpMM1 (CSR): wave per row, lane = out dim --------------------
__global__ void spmm1_csr(const int* __restrict__ rs,
                          const float2* __restrict__ sorted,
                          const float* __restrict__ W,
                          float* __restrict__ xw) {
    unsigned row  = blockIdx.x * 4u + (threadIdx.x >> 6);
    unsigned lane = threadIdx.x & 63u;
    if (row >= N_NODES) return;
    int start = rs[row], end = rs[row + 1];
    float acc = 0.0f;
    for (int p = start; p < end; p++) {
        float2 e = sorted[p];
        acc = fmaf(e.x, W[((unsigned)__float_as_int(e.y)) * OUT_DIM + lane], acc);
    }
    xw[row * OUT_DIM + lane] = acc;
}

// ---------------- SpMM2 (CSR) + ReLU -------------------------------------------
__global__ void spmm2_csr(const int* __restrict__ rs,
                          const float2* __restrict__ sorted,
                          const float* __restrict__ xw,
                          float* __restrict__ out) {
    unsigned row  = blockIdx.x * 4u + (threadIdx.x >> 6);
    unsigned lane = threadIdx.x & 63u;
    if (row >= N_NODES) return;
    int start = rs[row], end = rs[row + 1];
    float acc = 0.0f;
    for (int p = start; p < end; p++) {
        float2 e = sorted[p];
        acc = fmaf(e.x, xw[((unsigned)__float_as_int(e.y)) * OUT_DIM + lane], acc);
    }
    out[row * OUT_DIM + lane] = fmaxf(acc, 0.0f);
}

extern "C" void kernel_launch(void* const* d_in, const int* in_sizes, int n_in,
                              void* d_out, int out_size, void* d_ws, size_t ws_size,
                              hipStream_t stream) {
    const float* feat_values = (const float*)d_in[0];
    const float* W           = (const float*)d_in[1];
    const float* adj_values  = (const float*)d_in[2];
    const int*   feat_rows   = (const int*)d_in[3];
    const int*   feat_cols   = (const int*)d_in[4];
    const int*   adj_rows    = (const int*)d_in[5];
    const int*   adj_cols    = (const int*)d_in[6];
    float* out = (float*)d_out;

    // ---- workspace layout (bytes), total ~49.46 MB ----
    char* ws = (char*)d_ws;
    int* bc_x     = (int*)(ws + 0);         // 392 ints
    int* bc_a     = (int*)(ws + 2048);
    int* bstart_x = (int*)(ws + 4096);      // 392 ints (incl total)
    int* bstart_a = (int*)(ws + 6144);
    int* bcur_x   = (int*)(ws + 8192);
    int* bcur_a   = (int*)(ws + 10240);
    int* rs_x     = (int*)(ws + 12288);     // 100001 ints
    int* rs_a     = (int*)(ws + 412672);    // 100001 ints
    float2* gx    = (float2*)(ws + 813056);     // NNZ_X float2   (10.24 MB)
    float2* ga    = (float2*)(ws + 11053056);   // N_EDGES float2 (12.80 MB)
    float* xw     = (float*)(ws + 23853056);    // N*64 float     (25.60 MB)

    hipMemsetAsync(ws, 0, 4096, stream);    // bc_x + bc_a

    dim3 g391(391, 2);
    bucket_hist<<<g391, 256, 0, stream>>>(feat_rows, adj_rows, bc_x, bc_a);
    bucket_scan<<<dim3(1, 2), 256, 0, stream>>>(bc_x, bc_a, bstart_x, bstart_a, bcur_x, bcur_a);
    phase1<<<g391, 256, 0, stream>>>(feat_values, feat_rows, feat_cols,
                                     adj_values, adj_rows, adj_cols,
                                     bcur_x, bcur_a, gx, ga);
    phase2<<<g391, 256, 0, stream>>>(bstart_x, bstart_a, gx, ga, rs_x, rs_a);

    spmm1_csr<<<(N_NODES + 3) / 4, 256, 0, stream>>>(rs_x, gx, W, xw);
    spmm2_csr<<<(N_NODES + 3) / 4, 256, 0, stream>>>(rs_a, ga, xw, out);
}

// Round 5
// 299.475 us; speedup vs baseline: 2.4317x; 1.3067x over previous
//
#include <hip/hip_runtime.h>

#define N_NODES 100000
#define N_FEATS 256
#define OUT_DIM 64
#define NNZ_X   1280000
#define N_EDGES 1600000
#define NB      391     // ceil(N_NODES/256); bucket = row >> 8
#define CHUNK   4096    // entries per phase-1 block
#define P2CAP   6144    // phase-2 LDS capacity (avg bucket ~4092, +32 sigma margin)

// ---------------- JAX threefry2x32 (partitionable mode, verified R2) ----------------
__device__ __forceinline__ unsigned rotl32(unsigned x, unsigned d) {
    return (x << d) | (x >> (32u - d));
}

__device__ __forceinline__ float jax_uniform_42(unsigned e) {
    unsigned x0 = 0u, x1 = e;
    const unsigned ks0 = 0u, ks1 = 42u, ks2 = 0u ^ 42u ^ 0x1BD11BDAu;
    x0 += ks0; x1 += ks1;
#define TF_R(r) { x0 += x1; x1 = rotl32(x1, r); x1 ^= x0; }
    TF_R(13) TF_R(15) TF_R(26) TF_R(6)
    x0 += ks1; x1 += ks2 + 1u;
    TF_R(17) TF_R(29) TF_R(16) TF_R(24)
    x0 += ks2; x1 += ks0 + 2u;
    TF_R(13) TF_R(15) TF_R(26) TF_R(6)
    x0 += ks0; x1 += ks1 + 3u;
    TF_R(17) TF_R(29) TF_R(16) TF_R(24)
    x0 += ks1; x1 += ks2 + 4u;
    TF_R(13) TF_R(15) TF_R(26) TF_R(6)
    x0 += ks2; x1 += ks0 + 5u;
#undef TF_R
    unsigned bits = x0 ^ x1;
    return __uint_as_float((bits >> 9) | 0x3f800000u) - 1.0f;
}

// ---------------- bucket histogram: LDS-aggregated ----------------------------
__global__ void bucket_hist(const int* __restrict__ frows,
                            const int* __restrict__ arows,
                            int* __restrict__ bc_x, int* __restrict__ bc_a) {
    const int* rows = blockIdx.y ? arows : frows;
    int* bc         = blockIdx.y ? bc_a  : bc_x;
    const unsigned n = blockIdx.y ? N_EDGES : NNZ_X;
    __shared__ int h[NB];
    for (unsigned b = threadIdx.x; b < NB; b += 256u) h[b] = 0;
    __syncthreads();
    unsigned base = blockIdx.x * CHUNK;
    for (int k = 0; k < CHUNK / 256; k++) {
        unsigned i = base + k * 256u + threadIdx.x;
        if (i < n) atomicAdd(&h[(unsigned)rows[i] >> 8], 1);
    }
    __syncthreads();
    for (unsigned b = threadIdx.x; b < NB; b += 256u)
        if (h[b]) atomicAdd(&bc[b], h[b]);
}

// ---------------- scan 391 bucket totals -> starts + cursors ------------------
__global__ void bucket_scan(const int* __restrict__ bc_x, const int* __restrict__ bc_a,
                            int* __restrict__ bstart_x, int* __restrict__ bstart_a,
                            int* __restrict__ bcur_x, int* __restrict__ bcur_a) {
    const int* bc = blockIdx.y ? bc_a : bc_x;
    int* bst = blockIdx.y ? bstart_a : bstart_x;
    int* bcu = blockIdx.y ? bcur_a : bcur_x;
    __shared__ int c[512];
    __shared__ int s[256];
    unsigned t = threadIdx.x;
    c[2*t]   = (2*t   < NB) ? bc[2*t]   : 0;
    c[2*t+1] = (2*t+1 < NB) ? bc[2*t+1] : 0;
    s[t] = c[2*t] + c[2*t+1];
    __syncthreads();
    for (int off = 1; off < 256; off <<= 1) {
        int v = (t >= (unsigned)off) ? s[t - off] : 0;
        __syncthreads();
        s[t] += v;
        __syncthreads();
    }
    int excl = t ? s[t-1] : 0;
    if (2*t < NB)   { bst[2*t]   = excl;           bcu[2*t]   = excl; }
    if (2*t+1 < NB) { bst[2*t+1] = excl + c[2*t];  bcu[2*t+1] = excl + c[2*t]; }
    if (t == 255) bst[NB] = s[255];
}

// ---------------- phase 1: LDS-binned coarse scatter (coalesced writes) -------
__global__ void phase1(const float* __restrict__ fvals, const int* __restrict__ frows,
                       const int* __restrict__ fcols,
                       const float* __restrict__ avals, const int* __restrict__ arows,
                       const int* __restrict__ acols,
                       int* __restrict__ bcur_x, int* __restrict__ bcur_a,
                       float2* __restrict__ gx, float2* __restrict__ ga) {
    const int isA = blockIdx.y;
    const float* vals = isA ? avals : fvals;
    const int* rows   = isA ? arows : frows;
    const int* cols   = isA ? acols : fcols;
    int* bcur         = isA ? bcur_a : bcur_x;
    float2* dst       = isA ? ga : gx;
    const unsigned n  = isA ? N_EDGES : NNZ_X;

    unsigned t = threadIdx.x;
    unsigned base = blockIdx.x * CHUNK;
    if (base >= n) return;   // uniform per block

    __shared__ int cnt[512];
    __shared__ int start[512];
    __shared__ int cur[512];
    __shared__ int gbase[NB];
    __shared__ int s[256];
    __shared__ float2 stage[CHUNK];
    __shared__ unsigned short bArr[CHUNK];

    cnt[2*t] = 0; cnt[2*t+1] = 0;
    __syncthreads();
    for (int k = 0; k < CHUNK / 256; k++) {
        unsigned i = base + k * 256u + t;
        if (i < n) atomicAdd(&cnt[(unsigned)rows[i] >> 8], 1);
    }
    __syncthreads();
    s[t] = cnt[2*t] + cnt[2*t+1];
    __syncthreads();
    for (int off = 1; off < 256; off <<= 1) {
        int v = (t >= (unsigned)off) ? s[t - off] : 0;
        __syncthreads();
        s[t] += v;
        __syncthreads();
    }
    int excl = t ? s[t-1] : 0;
    int n_valid = s[255];
    start[2*t]   = excl;
    start[2*t+1] = excl + cnt[2*t];
    cur[2*t]     = excl;
    cur[2*t+1]   = excl + cnt[2*t];
    for (unsigned b = t; b < NB; b += 256u) {
        int cb = cnt[b];
        if (cb > 0) gbase[b] = atomicAdd(&bcur[b], cb);
    }
    __syncthreads();
    for (int k = 0; k < CHUNK / 256; k++) {
        unsigned i = base + k * 256u + t;
        if (i < n) {
            unsigned row = (unsigned)rows[i];
            unsigned b = row >> 8;
            float v = vals[i];
            if (!isA) {
                float u = jax_uniform_42(i);
                v = (floorf(0.9f + u) != 0.0f) ? v * (float)(1.0 / 0.9) : 0.0f;
            }
            unsigned packed = ((unsigned)cols[i] << 8) | (row & 255u);
            int p = atomicAdd(&cur[b], 1);
            float2 e; e.x = v; e.y = __int_as_float((int)packed);
            stage[p] = e;
            bArr[p] = (unsigned short)b;
        }
    }
    __syncthreads();
    for (int k = 0; k < CHUNK / 256; k++) {
        int sidx = k * 256 + (int)t;
        if (sidx < n_valid) {
            unsigned b = bArr[sidx];
            int gpos = gbase[b] + (sidx - start[b]);
            dst[gpos] = stage[sidx];
        }
    }
}

// ---------------- phase 2: per-bucket fine sort (in place) + CSR row starts ---
__global__ void phase2(const int* __restrict__ bstart_x, const int* __restrict__ bstart_a,
                       float2* __restrict__ gx, float2* __restrict__ ga,
                       int* __restrict__ rs_x, int* __restrict__ rs_a) {
    const int isA = blockIdx.y;
    const int* bst = isA ? bstart_a : bstart_x;
    float2* g      = isA ? ga : gx;
    int* rs        = isA ? rs_a : rs_x;
    const int total = isA ? N_EDGES : NNZ_X;

    __shared__ float2 ent[P2CAP];
    __shared__ int hist[256];
    __shared__ int cursor[256];

    unsigned t = threadIdx.x;
    unsigned b = blockIdx.x;
    int s0 = bst[b], s1 = bst[b + 1];
    int n = s1 - s0;
    hist[t] = 0;
    __syncthreads();
    for (int idx = (int)t; idx < n; idx += 256) {
        float2 e = g[s0 + idx];
        ent[idx] = e;
        atomicAdd(&hist[((unsigned)__float_as_int(e.y)) & 255u], 1);
    }
    __syncthreads();
    for (int off = 1; off < 256; off <<= 1) {
        int v = (t >= (unsigned)off) ? hist[t - off] : 0;
        __syncthreads();
        hist[t] += v;
        __syncthreads();
    }
    int excl = t ? hist[t - 1] : 0;
    cursor[t] = excl;
    unsigned row_global = (b << 8) + t;
    if (row_global < N_NODES) rs[row_global] = s0 + excl;
    if (b == NB - 1 && t == 0) rs[N_NODES] = total;
    __syncthreads();
    for (int idx = (int)t; idx < n; idx += 256) {
        float2 e = ent[idx];
        unsigned packed = (unsigned)__float_as_int(e.y);
        int p = atomicAdd(&cursor[packed & 255u], 1);
        float2 o; o.x = e.x; o.y = __int_as_float((int)(packed >> 8));
        g[s0 + p] = o;
    }
}

// ---------------- SpMM1 (CSR): wave per row; xw stored as bf16 -----------------
__global__ void spmm1_csr(const int* __restrict__ rs,
                          const float2* __restrict__ sorted,
                          const float* __restrict__ W,
                          unsigned short* __restrict__ xw) {
    unsigned row  = blockIdx.x * 4u + (threadIdx.x >> 6);
    unsigned lane = threadIdx.x & 63u;
    if (row >= N_NODES) return;
    int start = rs[row], end = rs[row + 1];
    float acc0 = 0.0f, acc1 = 0.0f;
    int p = start;
    for (; p + 2 <= end; p += 2) {
        float2 e0 = sorted[p];
        float2 e1 = sorted[p + 1];
        unsigned c0 = (unsigned)__float_as_int(e0.y);
        unsigned c1 = (unsigned)__float_as_int(e1.y);
        float w0 = W[c0 * OUT_DIM + lane];
        float w1 = W[c1 * OUT_DIM + lane];
        acc0 = fmaf(e0.x, w0, acc0);
        acc1 = fmaf(e1.x, w1, acc1);
    }
    if (p < end) {
        float2 e = sorted[p];
        acc0 = fmaf(e.x, W[((unsigned)__float_as_int(e.y)) * OUT_DIM + lane], acc0);
    }
    float acc = acc0 + acc1;
    // f32 -> bf16 round-to-nearest-even
    unsigned bits = __float_as_uint(acc);
    unsigned rounded = (bits + 0x7fffu + ((bits >> 16) & 1u)) >> 16;
    xw[row * OUT_DIM + lane] = (unsigned short)rounded;
}

// ---------------- SpMM2 (CSR) + ReLU: bf16 xw gather ---------------------------
__global__ void spmm2_csr(const int* __restrict__ rs,
                          const float2* __restrict__ sorted,
                          const unsigned short* __restrict__ xw,
                          float* __restrict__ out) {
    unsigned row  = blockIdx.x * 4u + (threadIdx.x >> 6);
    unsigned lane = threadIdx.x & 63u;
    if (row >= N_NODES) return;
    int start = rs[row], end = rs[row + 1];
    float acc0 = 0.0f, acc1 = 0.0f;
    int p = start;
    for (; p + 2 <= end; p += 2) {
        float2 e0 = sorted[p];
        float2 e1 = sorted[p + 1];
        unsigned c0 = (unsigned)__float_as_int(e0.y);
        unsigned c1 = (unsigned)__float_as_int(e1.y);
        float x0 = __uint_as_float((unsigned)xw[c0 * OUT_DIM + lane] << 16);
        float x1 = __uint_as_float((unsigned)xw[c1 * OUT_DIM + lane] << 16);
        acc0 = fmaf(e0.x, x0, acc0);
        acc1 = fmaf(e1.x, x1, acc1);
    }
    if (p < end) {
        float2 e = sorted[p];
        float x = __uint_as_float((unsigned)xw[((unsigned)__float_as_int(e.y)) * OUT_DIM + lane] << 16);
        acc0 = fmaf(e.x, x, acc0);
    }
    out[row * OUT_DIM + lane] = fmaxf(acc0 + acc1, 0.0f);
}

extern "C" void kernel_launch(void* const* d_in, const int* in_sizes, int n_in,
                              void* d_out, int out_size, void* d_ws, size_t ws_size,
                              hipStream_t stream) {
    const float* feat_values = (const float*)d_in[0];
    const float* W           = (const float*)d_in[1];
    const float* adj_values  = (const float*)d_in[2];
    const int*   feat_rows   = (const int*)d_in[3];
    const int*   feat_cols   = (const int*)d_in[4];
    const int*   adj_rows    = (const int*)d_in[5];
    const int*   adj_cols    = (const int*)d_in[6];
    float* out = (float*)d_out;

    // ---- workspace layout (bytes) ----
    char* ws = (char*)d_ws;
    int* bc_x     = (int*)(ws + 0);         // 392 ints
    int* bc_a     = (int*)(ws + 2048);
    int* bstart_x = (int*)(ws + 4096);      // 392 ints (incl total)
    int* bstart_a = (int*)(ws + 6144);
    int* bcur_x   = (int*)(ws + 8192);
    int* bcur_a   = (int*)(ws + 10240);
    int* rs_x     = (int*)(ws + 12288);     // 100001 ints
    int* rs_a     = (int*)(ws + 412672);    // 100001 ints
    float2* gx    = (float2*)(ws + 813056);     // NNZ_X float2   (10.24 MB)
    float2* ga    = (float2*)(ws + 11053056);   // N_EDGES float2 (12.80 MB)
    unsigned short* xw = (unsigned short*)(ws + 23853056);  // N*64 bf16 (12.8 MB)

    hipMemsetAsync(ws, 0, 4096, stream);    // bc_x + bc_a

    dim3 g391(391, 2);
    bucket_hist<<<g391, 256, 0, stream>>>(feat_rows, adj_rows, bc_x, bc_a);
    bucket_scan<<<dim3(1, 2), 256, 0, stream>>>(bc_x, bc_a, bstart_x, bstart_a, bcur_x, bcur_a);
    phase1<<<g391, 256, 0, stream>>>(feat_values, feat_rows, feat_cols,
                                     adj_values, adj_rows, adj_cols,
                                     bcur_x, bcur_a, gx, ga);
    phase2<<<g391, 256, 0, stream>>>(bstart_x, bstart_a, gx, ga, rs_x, rs_a);

    spmm1_csr<<<(N_NODES + 3) / 4, 256, 0, stream>>>(rs_x, gx, W, xw);
    spmm2_csr<<<(N_NODES + 3) / 4, 256, 0, stream>>>(rs_a, ga, xw, out);
}

// Round 6
// 279.533 us; speedup vs baseline: 2.6052x; 1.0713x over previous
//
#include <hip/hip_runtime.h>

#define N_NODES 100000
#define N_FEATS 256
#define OUT_DIM 64
#define NNZ_X   1280000
#define N_EDGES 1600000
#define NB      391     // ceil(N_NODES/256); bucket = row >> 8
#define CHUNK   4096    // entries per phase-1 block
#define P2CAP   6144    // phase-2 LDS capacity (avg bucket ~4092, +margin)

// ---------------- JAX threefry2x32 (partitionable mode, verified R2) ----------------
__device__ __forceinline__ unsigned rotl32(unsigned x, unsigned d) {
    return (x << d) | (x >> (32u - d));
}

__device__ __forceinline__ float jax_uniform_42(unsigned e) {
    unsigned x0 = 0u, x1 = e;
    const unsigned ks0 = 0u, ks1 = 42u, ks2 = 0u ^ 42u ^ 0x1BD11BDAu;
    x0 += ks0; x1 += ks1;
#define TF_R(r) { x0 += x1; x1 = rotl32(x1, r); x1 ^= x0; }
    TF_R(13) TF_R(15) TF_R(26) TF_R(6)
    x0 += ks1; x1 += ks2 + 1u;
    TF_R(17) TF_R(29) TF_R(16) TF_R(24)
    x0 += ks2; x1 += ks0 + 2u;
    TF_R(13) TF_R(15) TF_R(26) TF_R(6)
    x0 += ks0; x1 += ks1 + 3u;
    TF_R(17) TF_R(29) TF_R(16) TF_R(24)
    x0 += ks1; x1 += ks2 + 4u;
    TF_R(13) TF_R(15) TF_R(26) TF_R(6)
    x0 += ks2; x1 += ks0 + 5u;
#undef TF_R
    unsigned bits = x0 ^ x1;
    return __uint_as_float((bits >> 9) | 0x3f800000u) - 1.0f;
}

// ---------------- bucket histogram: LDS-aggregated ----------------------------
__global__ void bucket_hist(const int* __restrict__ frows,
                            const int* __restrict__ arows,
                            int* __restrict__ bc_x, int* __restrict__ bc_a) {
    const int* rows = blockIdx.y ? arows : frows;
    int* bc         = blockIdx.y ? bc_a  : bc_x;
    const unsigned n = blockIdx.y ? N_EDGES : NNZ_X;
    __shared__ int h[NB];
    for (unsigned b = threadIdx.x; b < NB; b += 256u) h[b] = 0;
    __syncthreads();
    unsigned base = blockIdx.x * CHUNK;
    for (int k = 0; k < CHUNK / 256; k++) {
        unsigned i = base + k * 256u + threadIdx.x;
        if (i < n) atomicAdd(&h[(unsigned)rows[i] >> 8], 1);
    }
    __syncthreads();
    for (unsigned b = threadIdx.x; b < NB; b += 256u)
        if (h[b]) atomicAdd(&bc[b], h[b]);
}

// ---------------- scan 391 bucket totals -> starts + cursors ------------------
__global__ void bucket_scan(const int* __restrict__ bc_x, const int* __restrict__ bc_a,
                            int* __restrict__ bstart_x, int* __restrict__ bstart_a,
                            int* __restrict__ bcur_x, int* __restrict__ bcur_a) {
    const int* bc = blockIdx.y ? bc_a : bc_x;
    int* bst = blockIdx.y ? bstart_a : bstart_x;
    int* bcu = blockIdx.y ? bcur_a : bcur_x;
    __shared__ int c[512];
    __shared__ int s[256];
    unsigned t = threadIdx.x;
    c[2*t]   = (2*t   < NB) ? bc[2*t]   : 0;
    c[2*t+1] = (2*t+1 < NB) ? bc[2*t+1] : 0;
    s[t] = c[2*t] + c[2*t+1];
    __syncthreads();
    for (int off = 1; off < 256; off <<= 1) {
        int v = (t >= (unsigned)off) ? s[t - off] : 0;
        __syncthreads();
        s[t] += v;
        __syncthreads();
    }
    int excl = t ? s[t-1] : 0;
    if (2*t < NB)   { bst[2*t]   = excl;           bcu[2*t]   = excl; }
    if (2*t+1 < NB) { bst[2*t+1] = excl + c[2*t];  bcu[2*t+1] = excl + c[2*t]; }
    if (t == 255) bst[NB] = s[255];
}

// ---------------- phase 1: LDS-binned coarse scatter (coalesced writes) -------
// LDS-lean version: stage only a u32 meta (bucket|rowlow|ilocal); the write
// pass re-reads cols/vals (L1-warm 16KB windows) and recomputes dropout.
__global__ void phase1(const float* __restrict__ fvals, const int* __restrict__ frows,
                       const int* __restrict__ fcols,
                       const float* __restrict__ avals, const int* __restrict__ arows,
                       const int* __restrict__ acols,
                       int* __restrict__ bcur_x, int* __restrict__ bcur_a,
                       float2* __restrict__ gx, float2* __restrict__ ga) {
    const int isA = blockIdx.y;
    const float* vals = isA ? avals : fvals;
    const int* rows   = isA ? arows : frows;
    const int* cols   = isA ? acols : fcols;
    int* bcur         = isA ? bcur_a : bcur_x;
    float2* dst       = isA ? ga : gx;
    const unsigned n  = isA ? N_EDGES : NNZ_X;

    unsigned t = threadIdx.x;
    unsigned base = blockIdx.x * CHUNK;
    if (base >= n) return;   // uniform per block

    __shared__ int cnt[512];
    __shared__ int start[512];
    __shared__ int cur[512];
    __shared__ int gbase[NB];
    __shared__ int s[256];
    __shared__ unsigned pArr[CHUNK];   // (b<<20)|(rowlow<<12)|ilocal

    cnt[2*t] = 0; cnt[2*t+1] = 0;
    __syncthreads();
    // pass 1: count buckets
    for (int k = 0; k < CHUNK / 256; k++) {
        unsigned i = base + k * 256u + t;
        if (i < n) atomicAdd(&cnt[(unsigned)rows[i] >> 8], 1);
    }
    __syncthreads();
    // exclusive scan of cnt
    s[t] = cnt[2*t] + cnt[2*t+1];
    __syncthreads();
    for (int off = 1; off < 256; off <<= 1) {
        int v = (t >= (unsigned)off) ? s[t - off] : 0;
        __syncthreads();
        s[t] += v;
        __syncthreads();
    }
    int excl = t ? s[t-1] : 0;
    int n_valid = s[255];
    start[2*t]   = excl;
    start[2*t+1] = excl + cnt[2*t];
    cur[2*t]     = excl;
    cur[2*t+1]   = excl + cnt[2*t];
    for (unsigned b = t; b < NB; b += 256u) {
        int cb = cnt[b];
        if (cb > 0) gbase[b] = atomicAdd(&bcur[b], cb);
    }
    __syncthreads();
    // pass 2: bucket-grouped permutation (meta only)
    for (int k = 0; k < CHUNK / 256; k++) {
        unsigned i = base + k * 256u + t;
        if (i < n) {
            unsigned row = (unsigned)rows[i];
            unsigned b = row >> 8;
            int p = atomicAdd(&cur[b], 1);
            pArr[p] = (b << 20) | ((row & 255u) << 12) | (i - base);
        }
    }
    __syncthreads();
    // pass 3: coalesced writes; re-read col/val, recompute dropout
    for (int k = 0; k < CHUNK / 256; k++) {
        int sidx = k * 256 + (int)t;
        if (sidx < n_valid) {
            unsigned m = pArr[sidx];
            unsigned b = m >> 20;
            unsigned rowlow = (m >> 12) & 255u;
            unsigned i = base + (m & 4095u);
            float v = vals[i];
            if (!isA) {
                float u = jax_uniform_42(i);
                v = (floorf(0.9f + u) != 0.0f) ? v * (float)(1.0 / 0.9) : 0.0f;
            }
            unsigned packed = ((unsigned)cols[i] << 8) | rowlow;
            float2 e; e.x = v; e.y = __int_as_float((int)packed);
            dst[gbase[b] + (sidx - start[b])] = e;
        }
    }
}

// ---------------- phase 2: per-bucket fine sort (in place) + CSR row starts ---
__global__ void phase2(const int* __restrict__ bstart_x, const int* __restrict__ bstart_a,
                       float2* __restrict__ gx, float2* __restrict__ ga,
                       int* __restrict__ rs_x, int* __restrict__ rs_a) {
    const int isA = blockIdx.y;
    const int* bst = isA ? bstart_a : bstart_x;
    float2* g      = isA ? ga : gx;
    int* rs        = isA ? rs_a : rs_x;
    const int total = isA ? N_EDGES : NNZ_X;

    __shared__ float2 ent[P2CAP];
    __shared__ int hist[256];
    __shared__ int cursor[256];

    unsigned t = threadIdx.x;
    unsigned b = blockIdx.x;
    int s0 = bst[b], s1 = bst[b + 1];
    int n = s1 - s0;
    hist[t] = 0;
    __syncthreads();
    for (int idx = (int)t; idx < n; idx += 256) {
        float2 e = g[s0 + idx];
        ent[idx] = e;
        atomicAdd(&hist[((unsigned)__float_as_int(e.y)) & 255u], 1);
    }
    __syncthreads();
    for (int off = 1; off < 256; off <<= 1) {
        int v = (t >= (unsigned)off) ? hist[t - off] : 0;
        __syncthreads();
        hist[t] += v;
        __syncthreads();
    }
    int excl = t ? hist[t - 1] : 0;
    cursor[t] = excl;
    unsigned row_global = (b << 8) + t;
    if (row_global < N_NODES) rs[row_global] = s0 + excl;
    if (b == NB - 1 && t == 0) rs[N_NODES] = total;
    __syncthreads();
    for (int idx = (int)t; idx < n; idx += 256) {
        float2 e = ent[idx];
        unsigned packed = (unsigned)__float_as_int(e.y);
        int p = atomicAdd(&cursor[packed & 255u], 1);
        float2 o; o.x = e.x; o.y = __int_as_float((int)(packed >> 8));
        g[s0 + p] = o;
    }
}

// ---------------- SpMM1 (CSR): wave per row; unroll 4; xw stored bf16 ----------
__global__ void spmm1_csr(const int* __restrict__ rs,
                          const float2* __restrict__ sorted,
                          const float* __restrict__ W,
                          unsigned short* __restrict__ xw) {
    unsigned row  = blockIdx.x * 4u + (threadIdx.x >> 6);
    unsigned lane = threadIdx.x & 63u;
    if (row >= N_NODES) return;
    int start = rs[row], end = rs[row + 1];
    float acc0 = 0.0f, acc1 = 0.0f, acc2 = 0.0f, acc3 = 0.0f;
    int p = start;
    for (; p + 4 <= end; p += 4) {
        float2 e0 = sorted[p];
        float2 e1 = sorted[p + 1];
        float2 e2 = sorted[p + 2];
        float2 e3 = sorted[p + 3];
        float w0 = W[((unsigned)__float_as_int(e0.y)) * OUT_DIM + lane];
        float w1 = W[((unsigned)__float_as_int(e1.y)) * OUT_DIM + lane];
        float w2 = W[((unsigned)__float_as_int(e2.y)) * OUT_DIM + lane];
        float w3 = W[((unsigned)__float_as_int(e3.y)) * OUT_DIM + lane];
        acc0 = fmaf(e0.x, w0, acc0);
        acc1 = fmaf(e1.x, w1, acc1);
        acc2 = fmaf(e2.x, w2, acc2);
        acc3 = fmaf(e3.x, w3, acc3);
    }
    for (; p < end; p++) {
        float2 e = sorted[p];
        acc0 = fmaf(e.x, W[((unsigned)__float_as_int(e.y)) * OUT_DIM + lane], acc0);
    }
    float acc = (acc0 + acc1) + (acc2 + acc3);
    unsigned bits = __float_as_uint(acc);
    unsigned rounded = (bits + 0x7fffu + ((bits >> 16) & 1u)) >> 16;
    xw[row * OUT_DIM + lane] = (unsigned short)rounded;
}

// ---------------- SpMM2 (CSR) + ReLU: unroll 4, bf16 xw gather -----------------
__global__ void spmm2_csr(const int* __restrict__ rs,
                          const float2* __restrict__ sorted,
                          const unsigned short* __restrict__ xw,
                          float* __restrict__ out) {
    unsigned row  = blockIdx.x * 4u + (threadIdx.x >> 6);
    unsigned lane = threadIdx.x & 63u;
    if (row >= N_NODES) return;
    int start = rs[row], end = rs[row + 1];
    float acc0 = 0.0f, acc1 = 0.0f, acc2 = 0.0f, acc3 = 0.0f;
    int p = start;
    for (; p + 4 <= end; p += 4) {
        float2 e0 = sorted[p];
        float2 e1 = sorted[p + 1];
        float2 e2 = sorted[p + 2];
        float2 e3 = sorted[p + 3];
        float x0 = __uint_as_float((unsigned)xw[((unsigned)__float_as_int(e0.y)) * OUT_DIM + lane] << 16);
        float x1 = __uint_as_float((unsigned)xw[((unsigned)__float_as_int(e1.y)) * OUT_DIM + lane] << 16);
        float x2 = __uint_as_float((unsigned)xw[((unsigned)__float_as_int(e2.y)) * OUT_DIM + lane] << 16);
        float x3 = __uint_as_float((unsigned)xw[((unsigned)__float_as_int(e3.y)) * OUT_DIM + lane] << 16);
        acc0 = fmaf(e0.x, x0, acc0);
        acc1 = fmaf(e1.x, x1, acc1);
        acc2 = fmaf(e2.x, x2, acc2);
        acc3 = fmaf(e3.x, x3, acc3);
    }
    for (; p < end; p++) {
        float2 e = sorted[p];
        float x = __uint_as_float((unsigned)xw[((unsigned)__float_as_int(e.y)) * OUT_DIM + lane] << 16);
        acc0 = fmaf(e.x, x, acc0);
    }
    out[row * OUT_DIM + lane] = fmaxf((acc0 + acc1) + (acc2 + acc3), 0.0f);
}

extern "C" void kernel_launch(void* const* d_in, const int* in_sizes, int n_in,
                              void* d_out, int out_size, void* d_ws, size_t ws_size,
                              hipStream_t stream) {
    const float* feat_values = (const float*)d_in[0];
    const float* W           = (const float*)d_in[1];
    const float* adj_values  = (const float*)d_in[2];
    const int*   feat_rows   = (const int*)d_in[3];
    const int*   feat_cols   = (const int*)d_in[4];
    const int*   adj_rows    = (const int*)d_in[5];
    const int*   adj_cols    = (const int*)d_in[6];
    float* out = (float*)d_out;

    // ---- workspace layout (bytes) ----
    char* ws = (char*)d_ws;
    int* bc_x     = (int*)(ws + 0);         // 392 ints
    int* bc_a     = (int*)(ws + 2048);
    int* bstart_x = (int*)(ws + 4096);      // 392 ints (incl total)
    int* bstart_a = (int*)(ws + 6144);
    int* bcur_x   = (int*)(ws + 8192);
    int* bcur_a   = (int*)(ws + 10240);
    int* rs_x     = (int*)(ws + 12288);     // 100001 ints
    int* rs_a     = (int*)(ws + 412672);    // 100001 ints
    float2* gx    = (float2*)(ws + 813056);     // NNZ_X float2   (10.24 MB)
    float2* ga    = (float2*)(ws + 11053056);   // N_EDGES float2 (12.80 MB)
    unsigned short* xw = (unsigned short*)(ws + 23853056);  // N*64 bf16 (12.8 MB)

    hipMemsetAsync(ws, 0, 4096, stream);    // bc_x + bc_a

    dim3 g391(391, 2);
    bucket_hist<<<g391, 256, 0, stream>>>(feat_rows, adj_rows, bc_x, bc_a);
    bucket_scan<<<dim3(1, 2), 256, 0, stream>>>(bc_x, bc_a, bstart_x, bstart_a, bcur_x, bcur_a);
    phase1<<<g391, 256, 0, stream>>>(feat_values, feat_rows, feat_cols,
                                     adj_values, adj_rows, adj_cols,
                                     bcur_x, bcur_a, gx, ga);
    phase2<<<g391, 256, 0, stream>>>(bstart_x, bstart_a, gx, ga, rs_x, rs_a);

    spmm1_csr<<<(N_NODES + 3) / 4, 256, 0, stream>>>(rs_x, gx, W, xw);
    spmm2_csr<<<(N_NODES + 3) / 4, 256, 0, stream>>>(rs_a, ga, xw, out);
}